// Round 9
// baseline (26.290 us; speedup 1.0000x reference)
//
#include <hip/hip_runtime.h>

constexpr int NW = 12;
constexpr int BT = 1024;  // 1 sample/block; state bits [wid:4][lane:6][j:2]
constexpr int NA = 4;     // amps per thread

typedef float f32x2 __attribute__((ext_vector_type(2)));

// ---- packed FP32 ops (validated R8) ----
__device__ __forceinline__ f32x2 pkmul(f32x2 a, f32x2 b) {
    f32x2 d; asm("v_pk_mul_f32 %0, %1, %2" : "=v"(d) : "v"(a), "v"(b)); return d;
}
__device__ __forceinline__ f32x2 pkfma(f32x2 a, f32x2 b, f32x2 c) {
    f32x2 d; asm("v_pk_fma_f32 %0, %1, %2, %3" : "=v"(d) : "v"(a), "v"(b), "v"(c)); return d;
}
// d.lo = -a.hi*b.lo + c.lo ; d.hi = a.lo*b.hi + c.hi
__device__ __forceinline__ f32x2 pkfma_swapneg(f32x2 a, f32x2 b, f32x2 c) {
    f32x2 d;
    asm("v_pk_fma_f32 %0, %1, %2, %3 op_sel:[1,0,0] op_sel_hi:[0,1,1] neg_lo:[1,0,0]"
        : "=v"(d) : "v"(a), "v"(b), "v"(c));
    return d;
}

template<bool PK> struct Ops {
    static __device__ __forceinline__ f32x2 cmul(f32x2 z, f32x2 ur, f32x2 ui) {
        if constexpr (PK) return pkfma_swapneg(z, ui, pkmul(z, ur));
        else { f32x2 r; r.x = ur.x*z.x - ui.x*z.y; r.y = ur.x*z.y + ui.x*z.x; return r; }
    }
    static __device__ __forceinline__ f32x2 cmac(f32x2 z, f32x2 ur, f32x2 ui, f32x2 acc) {
        if constexpr (PK) return pkfma_swapneg(z, ui, pkfma(z, ur, acc));
        else { f32x2 r; r.x = acc.x + ur.x*z.x - ui.x*z.y; r.y = acc.y + ur.x*z.y + ui.x*z.x; return r; }
    }
};

struct C2p { f32x2 r00,i00,r01,i01,r10,i10,r11,i11; };
struct St  { f32x2 z[NA]; };

// ---- cross-lane (validated R6) ----
template<int CTRL>
__device__ __forceinline__ float dppx(float v) {
    int r = __builtin_amdgcn_update_dpp(0, __builtin_bit_cast(int, v), CTRL, 0xF, 0xF, true);
    return __builtin_bit_cast(float, r);
}
template<int M>
__device__ __forceinline__ float lxor(float v, int bp32) {
    if constexpr (M == 1)      { return dppx<0xB1>(v); }
    else if constexpr (M == 2) { return dppx<0x4E>(v); }
    else if constexpr (M == 8) { return dppx<0x128>(v); }
    else if constexpr (M == 4) {
        int r = __builtin_amdgcn_ds_swizzle(__builtin_bit_cast(int, v), 0x101F);
        return __builtin_bit_cast(float, r);
    } else if constexpr (M == 16) {
        int r = __builtin_amdgcn_ds_swizzle(__builtin_bit_cast(int, v), 0x401F);
        return __builtin_bit_cast(float, r);
    } else {
        int r = __builtin_amdgcn_ds_bpermute(bp32, __builtin_bit_cast(int, v));
        return __builtin_bit_cast(float, r);
    }
}
template<int M>
__device__ __forceinline__ f32x2 lxor2(f32x2 z, int bp32) {
    f32x2 p; p.x = lxor<M>(z.x, bp32); p.y = lxor<M>(z.y, bp32); return p;
}

// ---- Rot gates ----
template<bool PK, int LM>
__device__ __forceinline__ void gate_local(St& s, const C2p& u) {
    #pragma unroll
    for (int j0 = 0; j0 < NA; ++j0) {
        if (j0 & LM) continue;
        const int j1 = j0 | LM;
        f32x2 z0 = s.z[j0], z1 = s.z[j1];
        s.z[j0] = Ops<PK>::cmac(z1, u.r01, u.i01, Ops<PK>::cmul(z0, u.r00, u.i00));
        s.z[j1] = Ops<PK>::cmac(z1, u.r11, u.i11, Ops<PK>::cmul(z0, u.r10, u.i10));
    }
}
template<bool PK, int M>
__device__ __forceinline__ void gate_lane(St& s, const C2p& u, int lane, int bp32) {
    const bool b = (lane & M) != 0;
    f32x2 ar = b ? u.r11 : u.r00, ai = b ? u.i11 : u.i00;
    f32x2 br = b ? u.r10 : u.r01, bi = b ? u.i10 : u.i01;
    #pragma unroll
    for (int j = 0; j < NA; ++j) {
        f32x2 p = lxor2<M>(s.z[j], bp32);
        s.z[j] = Ops<PK>::cmac(p, br, bi, Ops<PK>::cmul(s.z[j], ar, ai));
    }
}

// ---- LDS trips (store linear ex[(j<<10)|t]; one barrier; gather) ----
// swap J(2) <-> W3W2 (wid high bits)
__device__ __forceinline__ void trip_swap_hi(St& s, int t, int wid, int lane, f32x2* ex) {
    #pragma unroll
    for (int j = 0; j < NA; ++j) ex[(j<<10) | t] = s.z[j];
    __syncthreads();
    const int base = ((wid>>2)<<10) | ((wid&3)<<6) | lane;
    #pragma unroll
    for (int j = 0; j < NA; ++j) s.z[j] = ex[base | (j<<8)];
}
// swap J(2) <-> W1W0 (wid low bits)
__device__ __forceinline__ void trip_swap_lo(St& s, int t, int wid, int lane, f32x2* ex) {
    #pragma unroll
    for (int j = 0; j < NA; ++j) ex[(j<<10) | t] = s.z[j];
    __syncthreads();
    const int base = ((wid&3)<<10) | (((wid>>2)<<2)<<6) | lane;
    #pragma unroll
    for (int j = 0; j < NA; ++j) s.z[j] = ex[base | (j<<6)];
}
// ring1 (r=1 CNOT chain) as one GF(2) gather, in layout B, target layout B
__device__ __forceinline__ void trip_ring1(St& s, int t, int wid, int lane, f32x2* ex) {
    #pragma unroll
    for (int j = 0; j < NA; ++j) ex[(j<<10) | t] = s.z[j];
    __syncthreads();
    const int lg = lane ^ (lane >> 1);
    const int wg = (wid ^ (wid >> 1)) ^ ((lane & 1) << 3) ^ ((wid >> 2) & 1);
    const int jsel = (wid & 1) << 1;
    #pragma unroll
    for (int j = 0; j < NA; ++j) {
        const int jx = (j ^ (j >> 1)) ^ jsel;
        const int lx = lg ^ ((j & 1) << 5);
        s.z[j] = ex[(jx << 10) | (wg << 6) | lx];
    }
}

// ---- full circuit ----
template<bool PK>
__device__ __forceinline__ void run_all(St& s, f32x2* ex0, f32x2* ex1,
                                        const f32x2* __restrict__ coef,
                                        int t, int lane, int wid, int bp32) {
    auto ld = [&](int g) -> C2p {
        C2p u;
        u.r00 = coef[g*8+0]; u.i00 = coef[g*8+1];
        u.r01 = coef[g*8+2]; u.i01 = coef[g*8+3];
        u.r10 = coef[g*8+4]; u.i10 = coef[g*8+5];
        u.r11 = coef[g*8+6]; u.i11 = coef[g*8+7];
        return u;
    };
    // ===== layer 0 ===== (L0: wires 0-3 wave, 4-9 lane, 10-11 local)
    { C2p u = ld(10); gate_local<PK,2>(s, u); }
    { C2p u = ld(11); gate_local<PK,1>(s, u); }
    { C2p u = ld(4);  gate_lane<PK,32>(s, u, lane, bp32); }
    { C2p u = ld(5);  gate_lane<PK,16>(s, u, lane, bp32); }
    { C2p u = ld(6);  gate_lane<PK,8>(s, u, lane, bp32); }
    { C2p u = ld(7);  gate_lane<PK,4>(s, u, lane, bp32); }
    { C2p u = ld(8);  gate_lane<PK,2>(s, u, lane, bp32); }
    { C2p u = ld(9);  gate_lane<PK,1>(s, u, lane, bp32); }
    trip_swap_hi(s, t, wid, lane, ex0);       // -> A: J=(0,1), W3W2=(10,11)
    { C2p u = ld(0);  gate_local<PK,2>(s, u); }
    { C2p u = ld(1);  gate_local<PK,1>(s, u); }
    trip_swap_lo(s, t, wid, lane, ex1);       // -> B: J=(2,3), W1W0=(0,1)
    { C2p u = ld(2);  gate_local<PK,2>(s, u); }
    { C2p u = ld(3);  gate_local<PK,1>(s, u); }
    trip_ring1(s, t, wid, lane, ex0);         // whole CNOT ring r=1, stays in B
    // ===== layer 1 ===== (B: wires 2,3 local; 4-9 lane; 0,1=W1W0; 10,11=W3W2)
    { C2p u = ld(14); gate_local<PK,2>(s, u); }
    { C2p u = ld(15); gate_local<PK,1>(s, u); }
    { C2p u = ld(16); gate_lane<PK,32>(s, u, lane, bp32); }
    { C2p u = ld(17); gate_lane<PK,16>(s, u, lane, bp32); }
    { C2p u = ld(18); gate_lane<PK,8>(s, u, lane, bp32); }
    { C2p u = ld(19); gate_lane<PK,4>(s, u, lane, bp32); }
    { C2p u = ld(20); gate_lane<PK,2>(s, u, lane, bp32); }
    { C2p u = ld(21); gate_lane<PK,1>(s, u, lane, bp32); }
    trip_swap_hi(s, t, wid, lane, ex1);       // -> C: J=(10,11), W3W2=(2,3)
    { C2p u = ld(22); gate_local<PK,2>(s, u); }
    { C2p u = ld(23); gate_local<PK,1>(s, u); }
    trip_swap_lo(s, t, wid, lane, ex0);       // -> D: J=(0,1), W1W0=(10,11)
    { C2p u = ld(12); gate_local<PK,2>(s, u); }
    { C2p u = ld(13); gate_local<PK,1>(s, u); }
    // CNOT ring r=2 is fused into the epilogue (zsign evaluated at permuted index)
}

// ---- prep: splat the 24 shared Rot matrices into d_ws ----
__global__ void prep_kernel(const float* __restrict__ var, float* __restrict__ ws) {
    const int g = threadIdx.x;
    if (g >= 24) return;
    const float phi   = var[g*3+0];
    const float theta = var[g*3+1];
    const float omega = var[g*3+2];
    float st, ct; sincosf(0.5f*theta, &st, &ct);
    float sp, cp; sincosf(-0.5f*(phi+omega), &sp, &cp);
    float sm, cm; sincosf(-0.5f*(phi-omega), &sm, &cm);
    const float v[8] = { cp*ct,  sp*ct,    // u00
                        -cm*st,  sm*st,    // u01
                         cm*st,  sm*st,    // u10
                         cp*ct, -sp*ct };  // u11
    #pragma unroll
    for (int k = 0; k < 8; ++k) {
        ws[g*16 + 2*k]     = v[k];
        ws[g*16 + 2*k + 1] = v[k];
    }
}

__global__ __launch_bounds__(BT, 8)
void qnn_kernel(const float* __restrict__ x, const float* __restrict__ hw,
                const float* __restrict__ hb, const f32x2* __restrict__ coef,
                float* __restrict__ out)
{
    __shared__ f32x2 ex[2][4096];      // 64 KiB -> 2 blocks/CU, 32 waves/CU
    __shared__ float sxc[12], sxs[12];
    __shared__ float wavesum[16];

    const int t    = threadIdx.x;
    const int b    = blockIdx.x;
    const int lane = t & 63;
    const int wid  = t >> 6;           // 4 bits
    const int bp32 = (lane ^ 32) << 2;

    // packed-op semantics self-check (exact fp32; asm can't fold)
    bool pk_ok;
    {
        f32x2 z = {1.0f, 2.0f}, ur2 = {3.0f, 3.0f}, ui2 = {5.0f, 5.0f}, acc = {0.25f, -0.5f};
        f32x2 r = pkfma_swapneg(z, ui2, pkfma(z, ur2, acc));
        pk_ok = (r.x == -6.75f) && (r.y == 10.5f);
    }

    if (t < 12) {
        float sn, cs; sincosf(0.5f * x[b*NW + t], &sn, &cs);
        sxs[t] = sn; sxc[t] = cs;
    }
    __syncthreads();

    // product state after RY encoding (L0): wires 0..9 <-> t bits 9..0, wires 10,11 <-> j1,j0
    St s;
    float F = 1.0f;
    #pragma unroll
    for (int w = 0; w < 10; ++w)
        F *= ((t >> (9 - w)) & 1) ? sxs[w] : sxc[w];
    #pragma unroll
    for (int j = 0; j < NA; ++j) {
        float v = F;
        v *= (j & 2) ? sxs[10] : sxc[10];
        v *= (j & 1) ? sxs[11] : sxc[11];
        s.z[j] = f32x2{v, 0.0f};
    }

    if (pk_ok) run_all<true >(s, ex[0], ex[1], coef, t, lane, wid, bp32);
    else       run_all<false>(s, ex[0], ex[1], coef, t, lane, wid, bp32);

    // ---- epilogue in layout D with ring2 (r=2) fused via y = M2·x ----
    // D: x0=j1 x1=j0 | x2=t9 x3=t8 | x4..x9 = t5..t0 | x10=t7 x11=t6
    float h[NW];
    #pragma unroll
    for (int w = 0; w < NW; ++w) h[w] = hw[w];
    const int e1 = (t >> 9) & 1;
    const int e2 = e1 ^ ((t >> 5) & 1);
    const int e3 = e2 ^ ((t >> 3) & 1);
    const int e4 = e3 ^ ((t >> 1) & 1);
    const int e5 = e4 ^ ((t >> 7) & 1);
    const int o1 = (t >> 8) & 1;
    const int o2 = o1 ^ ((t >> 4) & 1);
    const int o3 = o2 ^ ((t >> 2) & 1);
    const int o4 = o3 ^ (t & 1);
    const int o5 = o4 ^ ((t >> 6) & 1);
    const float A = (e1 ? -h[2] : h[2]) + (e2 ? -h[4] : h[4]) + (e3 ? -h[6] : h[6])
                  + (e4 ? -h[8] : h[8]) + (e5 ? -h[10] : h[10]);
    const float B = (o1 ? -h[3] : h[3]) + (o2 ? -h[5] : h[5]) + (o3 ? -h[7] : h[7])
                  + (o4 ? -h[9] : h[9]) + (o5 ? -h[11] : h[11]);
    const float C = (e5 ? -h[0] : h[0]) + (o5 ? -h[1] : h[1]);

    float acc = 0.0f;
    #pragma unroll
    for (int j = 0; j < NA; ++j) {
        const float pr = s.z[j].x*s.z[j].x + s.z[j].y*s.z[j].y;
        const float zz = C + ((j & 2) ? -A : A) + ((j & 1) ? -B : B);
        acc += pr * zz;
    }
    #pragma unroll
    for (int off = 32; off > 0; off >>= 1) acc += __shfl_down(acc, off, 64);
    if (lane == 0) wavesum[wid] = acc;
    __syncthreads();
    if (t == 0) {
        float r = hb[0];
        #pragma unroll
        for (int wv = 0; wv < 16; ++wv) r += wavesum[wv];
        out[b] = r;
    }
}

extern "C" void kernel_launch(void* const* d_in, const int* in_sizes, int n_in,
                              void* d_out, int out_size, void* d_ws, size_t ws_size,
                              hipStream_t stream) {
    const float* x   = (const float*)d_in[0];
    const float* var = (const float*)d_in[1];
    const float* hw  = (const float*)d_in[2];
    const float* hb  = (const float*)d_in[3];
    float* out = (float*)d_out;
    prep_kernel<<<1, 32, 0, stream>>>(var, (float*)d_ws);
    qnn_kernel<<<out_size, BT, 0, stream>>>(x, hw, hb, (const f32x2*)d_ws, out);
}

// Round 10
// 19.012 us; speedup vs baseline: 1.3828x; 1.3828x over previous
//
#include <hip/hip_runtime.h>

constexpr int NW = 12;
constexpr int BT = 512;   // 1 sample/block; state bits [wid:3][lane:6][j:3]
constexpr int NA = 8;     // amps per thread

typedef float f32x2 __attribute__((ext_vector_type(2)));

// ---- packed FP32 ops (validated R8) ----
__device__ __forceinline__ f32x2 pkmul(f32x2 a, f32x2 b) {
    f32x2 d; asm("v_pk_mul_f32 %0, %1, %2" : "=v"(d) : "v"(a), "v"(b)); return d;
}
__device__ __forceinline__ f32x2 pkfma(f32x2 a, f32x2 b, f32x2 c) {
    f32x2 d; asm("v_pk_fma_f32 %0, %1, %2, %3" : "=v"(d) : "v"(a), "v"(b), "v"(c)); return d;
}
// d.lo = -a.hi*b.lo + c.lo ; d.hi = a.lo*b.hi + c.hi
__device__ __forceinline__ f32x2 pkfma_swapneg(f32x2 a, f32x2 b, f32x2 c) {
    f32x2 d;
    asm("v_pk_fma_f32 %0, %1, %2, %3 op_sel:[1,0,0] op_sel_hi:[0,1,1] neg_lo:[1,0,0]"
        : "=v"(d) : "v"(a), "v"(b), "v"(c));
    return d;
}

template<bool PK> struct Ops {
    static __device__ __forceinline__ f32x2 cmul(f32x2 z, f32x2 ur, f32x2 ui) {
        if constexpr (PK) return pkfma_swapneg(z, ui, pkmul(z, ur));
        else { f32x2 r; r.x = ur.x*z.x - ui.x*z.y; r.y = ur.x*z.y + ui.x*z.x; return r; }
    }
    static __device__ __forceinline__ f32x2 cmac(f32x2 z, f32x2 ur, f32x2 ui, f32x2 acc) {
        if constexpr (PK) return pkfma_swapneg(z, ui, pkfma(z, ur, acc));
        else { f32x2 r; r.x = acc.x + ur.x*z.x - ui.x*z.y; r.y = acc.y + ur.x*z.y + ui.x*z.x; return r; }
    }
};

struct C2p { f32x2 r00,i00,r01,i01,r10,i10,r11,i11; };
struct St  { f32x2 z[NA]; };

// ---- cross-lane (validated R6) ----
template<int CTRL>
__device__ __forceinline__ float dppx(float v) {
    int r = __builtin_amdgcn_update_dpp(0, __builtin_bit_cast(int, v), CTRL, 0xF, 0xF, true);
    return __builtin_bit_cast(float, r);
}
template<int M>
__device__ __forceinline__ float lxor(float v, int bp32) {
    if constexpr (M == 1)      { return dppx<0xB1>(v); }
    else if constexpr (M == 2) { return dppx<0x4E>(v); }
    else if constexpr (M == 8) { return dppx<0x128>(v); }
    else if constexpr (M == 4) {
        int r = __builtin_amdgcn_ds_swizzle(__builtin_bit_cast(int, v), 0x101F);
        return __builtin_bit_cast(float, r);
    } else if constexpr (M == 16) {
        int r = __builtin_amdgcn_ds_swizzle(__builtin_bit_cast(int, v), 0x401F);
        return __builtin_bit_cast(float, r);
    } else {
        int r = __builtin_amdgcn_ds_bpermute(bp32, __builtin_bit_cast(int, v));
        return __builtin_bit_cast(float, r);
    }
}
template<int M>
__device__ __forceinline__ f32x2 lxor2(f32x2 z, int bp32) {
    f32x2 p; p.x = lxor<M>(z.x, bp32); p.y = lxor<M>(z.y, bp32); return p;
}

// ---- Rot gates ----
template<bool PK, int LM>
__device__ __forceinline__ void gate_local(St& s, const C2p& u) {
    #pragma unroll
    for (int j0 = 0; j0 < NA; ++j0) {
        if (j0 & LM) continue;
        const int j1 = j0 | LM;
        f32x2 z0 = s.z[j0], z1 = s.z[j1];
        s.z[j0] = Ops<PK>::cmac(z1, u.r01, u.i01, Ops<PK>::cmul(z0, u.r00, u.i00));
        s.z[j1] = Ops<PK>::cmac(z1, u.r11, u.i11, Ops<PK>::cmul(z0, u.r10, u.i10));
    }
}
template<bool PK, int M>
__device__ __forceinline__ void gate_lane(St& s, const C2p& u, int lane, int bp32) {
    const bool b = (lane & M) != 0;
    f32x2 ar = b ? u.r11 : u.r00, ai = b ? u.i11 : u.i00;
    f32x2 br = b ? u.r10 : u.r01, bi = b ? u.i10 : u.i01;
    #pragma unroll
    for (int j = 0; j < NA; ++j) {
        f32x2 p = lxor2<M>(s.z[j], bp32);
        s.z[j] = Ops<PK>::cmac(p, br, bi, Ops<PK>::cmul(s.z[j], ar, ai));
    }
}

// ---- transpose: swap 3 wid bits with 3 j bits (one barrier; involution; validated R7/R8) ----
__device__ __forceinline__ void transpose_wl(St& s, int t, int wid, int lane, f32x2* ex) {
    #pragma unroll
    for (int j = 0; j < NA; ++j) ex[(j<<9) | t] = s.z[j];
    __syncthreads();
    #pragma unroll
    for (int j = 0; j < NA; ++j) s.z[j] = ex[(wid<<9) | (j<<6) | lane];
}

// ---- entire CNOT ring r=1 as ONE GF(2) gather (in L1 layout; one barrier) ----
// Inverse map: x0=y0^y11, x1=y0^y1^y11, x_k=y_k^y_{k-1}  =>  gray-code addressing:
//   src_j    = gray3(j)   ^ (W0 ? 6 : 0)
//   src_wid  = gray3(wid) ^ ((lane&1)<<2)
//   src_lane = gray6(lane)^ ((j&1)<<5)
__device__ __forceinline__ void trip_ring1(St& s, int t, int wid, int lane, f32x2* ex) {
    #pragma unroll
    for (int j = 0; j < NA; ++j) ex[(j<<9) | t] = s.z[j];
    __syncthreads();
    const int glane = lane ^ (lane >> 1);
    const int gwid6 = (((wid ^ (wid >> 1)) ^ ((lane & 1) << 2)) << 6);
    const int jx    = (wid & 1) ? 6 : 0;
    #pragma unroll
    for (int j = 0; j < NA; ++j) {
        const int gj = ((j ^ (j >> 1)) ^ jx) << 9;
        s.z[j] = ex[gj | gwid6 | (glane ^ ((j & 1) << 5))];
    }
}

// ---- full circuit; CNOT ring r=2 is fused into the epilogue ----
template<bool PK>
__device__ __forceinline__ void run_all(St& s, f32x2* ex0, f32x2* ex1,
                                        const f32x2 (*rotu)[8],
                                        int t, int lane, int wid, int bp32) {
    auto ld = [&](int g) -> C2p {
        C2p u;
        u.r00 = rotu[g][0]; u.i00 = rotu[g][1];
        u.r01 = rotu[g][2]; u.i01 = rotu[g][3];
        u.r10 = rotu[g][4]; u.i10 = rotu[g][5];
        u.r11 = rotu[g][6]; u.i11 = rotu[g][7];
        return u;
    };
    // ===== layer 0 ===== (L0: wires 0-2=wid, 3-8=lane, 9-11=j)
    { C2p u = ld(9);  gate_local<PK,4>(s, u); }
    { C2p u = ld(10); gate_local<PK,2>(s, u); }
    { C2p u = ld(11); gate_local<PK,1>(s, u); }
    { C2p u = ld(3);  gate_lane<PK,32>(s, u, lane, bp32); }
    { C2p u = ld(4);  gate_lane<PK,16>(s, u, lane, bp32); }
    { C2p u = ld(5);  gate_lane<PK,8>(s, u, lane, bp32); }
    { C2p u = ld(6);  gate_lane<PK,4>(s, u, lane, bp32); }
    { C2p u = ld(7);  gate_lane<PK,2>(s, u, lane, bp32); }
    { C2p u = ld(8);  gate_lane<PK,1>(s, u, lane, bp32); }
    transpose_wl(s, t, wid, lane, ex0);       // -> L1: wires 0-2=j, 9-11=wid
    { C2p u = ld(0);  gate_local<PK,4>(s, u); }
    { C2p u = ld(1);  gate_local<PK,2>(s, u); }
    { C2p u = ld(2);  gate_local<PK,1>(s, u); }
    trip_ring1(s, t, wid, lane, ex1);         // whole CNOT ring r=1 (stays L1)
    // ===== layer 1 ===== (L1)
    { C2p u = ld(12); gate_local<PK,4>(s, u); }
    { C2p u = ld(13); gate_local<PK,2>(s, u); }
    { C2p u = ld(14); gate_local<PK,1>(s, u); }
    { C2p u = ld(15); gate_lane<PK,32>(s, u, lane, bp32); }
    { C2p u = ld(16); gate_lane<PK,16>(s, u, lane, bp32); }
    { C2p u = ld(17); gate_lane<PK,8>(s, u, lane, bp32); }
    { C2p u = ld(18); gate_lane<PK,4>(s, u, lane, bp32); }
    { C2p u = ld(19); gate_lane<PK,2>(s, u, lane, bp32); }
    { C2p u = ld(20); gate_lane<PK,1>(s, u, lane, bp32); }
    transpose_wl(s, t, wid, lane, ex0);       // -> back to L0
    { C2p u = ld(21); gate_local<PK,4>(s, u); }
    { C2p u = ld(22); gate_local<PK,2>(s, u); }
    { C2p u = ld(23); gate_local<PK,1>(s, u); }
    // ring r=2 fused into epilogue via z(M2·x)
}

__global__ __launch_bounds__(BT)
void qnn_kernel(const float* __restrict__ x, const float* __restrict__ var,
                const float* __restrict__ hw, const float* __restrict__ hb,
                float* __restrict__ out)
{
    __shared__ f32x2 ex[2][NA * BT];   // 64 KiB -> 2 blocks/CU
    __shared__ f32x2 rotu[24][8];
    __shared__ float sxc[12], sxs[12];
    __shared__ float wavesum[8];

    const int t    = threadIdx.x;
    const int b    = blockIdx.x;
    const int lane = t & 63;
    const int wid  = t >> 6;
    const int bp32 = (lane ^ 32) << 2;

    // packed-op semantics self-check (exact fp32; asm can't fold)
    bool pk_ok;
    {
        f32x2 z = {1.0f, 2.0f}, ur2 = {3.0f, 3.0f}, ui2 = {5.0f, 5.0f}, acc = {0.25f, -0.5f};
        f32x2 r = pkfma_swapneg(z, ui2, pkfma(z, ur2, acc));
        pk_ok = (r.x == -6.75f) && (r.y == 10.5f);
    }

    if (t < 12) {
        float sn, cs; sincosf(0.5f * x[b*NW + t], &sn, &cs);
        sxs[t] = sn; sxc[t] = cs;
    }
    if (t < 24) {
        const float phi   = var[t*3+0];
        const float theta = var[t*3+1];
        const float omega = var[t*3+2];
        float st, ct; sincosf(0.5f*theta, &st, &ct);
        float sp, cp; sincosf(-0.5f*(phi+omega), &sp, &cp);
        float sm, cm; sincosf(-0.5f*(phi-omega), &sm, &cm);
        const float v0r =  cp*ct, v0i =  sp*ct;   // u00
        const float v1r = -cm*st, v1i =  sm*st;   // u01
        const float v2r =  cm*st, v2i =  sm*st;   // u10
        const float v3r =  cp*ct, v3i = -sp*ct;   // u11
        rotu[t][0] = f32x2{v0r, v0r}; rotu[t][1] = f32x2{v0i, v0i};
        rotu[t][2] = f32x2{v1r, v1r}; rotu[t][3] = f32x2{v1i, v1i};
        rotu[t][4] = f32x2{v2r, v2r}; rotu[t][5] = f32x2{v2i, v2i};
        rotu[t][6] = f32x2{v3r, v3r}; rotu[t][7] = f32x2{v3i, v3i};
    }
    __syncthreads();

    // product state after RY encoding (L0: amp = [wid|lane|j], wire w <-> bit 11-w)
    St s;
    float F = 1.0f;
    #pragma unroll
    for (int w = 0; w < 9; ++w)
        F *= ((t >> (8 - w)) & 1) ? sxs[w] : sxc[w];
    #pragma unroll
    for (int j = 0; j < NA; ++j) {
        float v = F;
        v *= (j & 4) ? sxs[9]  : sxc[9];
        v *= (j & 2) ? sxs[10] : sxc[10];
        v *= (j & 1) ? sxs[11] : sxc[11];
        s.z[j] = f32x2{v, 0.0f};
    }

    if (pk_ok) run_all<true >(s, ex[0], ex[1], rotu, t, lane, wid, bp32);
    else       run_all<false>(s, ex[0], ex[1], rotu, t, lane, wid, bp32);

    // ---- epilogue: probs -> z(M2 x) -> head (ring r=2 fused) ----
    // L0: x0=W2 x1=W1 x2=W0 | x3..x8 = l5..l0 | x9=j2 x10=j1 x11=j0
    float h[NW];
    #pragma unroll
    for (int w = 0; w < NW; ++w) h[w] = hw[w];
    const int W = wid, l = lane;
    const int s2 = ((W >> 2) ^ W) & 1;              // y2  = W2^W0
    const int s3 = ((W >> 1) ^ (l >> 5)) & 1;       // y3  = W1^l5
    const int s4 = s2 ^ ((l >> 4) & 1);             // y4
    const int s5 = s3 ^ ((l >> 3) & 1);             // y5
    const int s6 = s4 ^ ((l >> 2) & 1);             // y6
    const int s7 = s5 ^ ((l >> 1) & 1);             // y7
    const int s8 = s6 ^ (l & 1);                    // y8
    const int c0 = (W ^ (l >> 4) ^ (l >> 2) ^ l) & 1;               // W0^l4^l2^l0
    const int c10 = c0 ^ ((W >> 2) & 1);                            // ^W2
    const int c9 = ((W >> 1) ^ (l >> 5) ^ (l >> 3) ^ (l >> 1)) & 1; // W1^l5^l3^l1
    const int c1 = c9 ^ ((W >> 1) & 1);                             // l5^l3^l1

    const float base =
        (s2 ? -h[2] : h[2]) + (s3 ? -h[3] : h[3]) + (s4 ? -h[4] : h[4]) +
        (s5 ? -h[5] : h[5]) + (s6 ? -h[6] : h[6]) + (s7 ? -h[7] : h[7]) +
        (s8 ? -h[8] : h[8]);
    const float A  = (c0 ? -h[0] : h[0]) + (c10 ? -h[10] : h[10]);   // * (-1)^j1
    const float B  = (c1 ? -h[1] : h[1]) + (c9  ? -h[11] : h[11]);   // * (-1)^(j2^j0)
    const float Cc = (c9 ? -h[9] : h[9]);                            // * (-1)^j2

    float acc = 0.0f;
    #pragma unroll
    for (int j = 0; j < NA; ++j) {
        const float pr = s.z[j].x*s.z[j].x + s.z[j].y*s.z[j].y;
        float zz = base;
        zz += (j & 2) ? -A : A;
        zz += (j & 4) ? -Cc : Cc;
        zz += (((j >> 2) ^ j) & 1) ? -B : B;
        acc += pr * zz;
    }
    #pragma unroll
    for (int off = 32; off > 0; off >>= 1) acc += __shfl_down(acc, off, 64);
    if (lane == 0) wavesum[wid] = acc;
    __syncthreads();
    if (t == 0) {
        float r = hb[0];
        #pragma unroll
        for (int wv = 0; wv < 8; ++wv) r += wavesum[wv];
        out[b] = r;
    }
}

extern "C" void kernel_launch(void* const* d_in, const int* in_sizes, int n_in,
                              void* d_out, int out_size, void* d_ws, size_t ws_size,
                              hipStream_t stream) {
    const float* x   = (const float*)d_in[0];
    const float* var = (const float*)d_in[1];
    const float* hw  = (const float*)d_in[2];
    const float* hb  = (const float*)d_in[3];
    float* out = (float*)d_out;
    qnn_kernel<<<out_size, BT, 0, stream>>>(x, var, hw, hb, out);
}

// Round 11
// 14.413 us; speedup vs baseline: 1.8240x; 1.3191x over previous
//
#include <hip/hip_runtime.h>

constexpr int NW = 12;
constexpr int BT = 512;   // 1 sample/block; state bits [wid:3][lane:6][j:3]
constexpr int NA = 8;     // amps per thread

typedef float f32x2 __attribute__((ext_vector_type(2)));
typedef float f32x4 __attribute__((ext_vector_type(4)));

// ---- packed FP32 ops (validated R8) ----
__device__ __forceinline__ f32x2 pkmul(f32x2 a, f32x2 b) {
    f32x2 d; asm("v_pk_mul_f32 %0, %1, %2" : "=v"(d) : "v"(a), "v"(b)); return d;
}
__device__ __forceinline__ f32x2 pkfma(f32x2 a, f32x2 b, f32x2 c) {
    f32x2 d; asm("v_pk_fma_f32 %0, %1, %2, %3" : "=v"(d) : "v"(a), "v"(b), "v"(c)); return d;
}
// d.lo = -a.hi*b.lo + c.lo ; d.hi = a.lo*b.hi + c.hi
__device__ __forceinline__ f32x2 pkfma_swapneg(f32x2 a, f32x2 b, f32x2 c) {
    f32x2 d;
    asm("v_pk_fma_f32 %0, %1, %2, %3 op_sel:[1,0,0] op_sel_hi:[0,1,1] neg_lo:[1,0,0]"
        : "=v"(d) : "v"(a), "v"(b), "v"(c));
    return d;
}

template<bool PK> struct Ops {
    static __device__ __forceinline__ f32x2 cmul(f32x2 z, f32x2 ur, f32x2 ui) {
        if constexpr (PK) return pkfma_swapneg(z, ui, pkmul(z, ur));
        else { f32x2 r; r.x = ur.x*z.x - ui.x*z.y; r.y = ur.x*z.y + ui.x*z.x; return r; }
    }
    static __device__ __forceinline__ f32x2 cmac(f32x2 z, f32x2 ur, f32x2 ui, f32x2 acc) {
        if constexpr (PK) return pkfma_swapneg(z, ui, pkfma(z, ur, acc));
        else { f32x2 r; r.x = acc.x + ur.x*z.x - ui.x*z.y; r.y = acc.y + ur.x*z.y + ui.x*z.x; return r; }
    }
};

struct C2p { f32x2 r00,i00,r01,i01,r10,i10,r11,i11; };
struct St  { f32x2 z[NA]; };

// ---- cross-lane (validated R6) ----
template<int CTRL>
__device__ __forceinline__ float dppx(float v) {
    int r = __builtin_amdgcn_update_dpp(0, __builtin_bit_cast(int, v), CTRL, 0xF, 0xF, true);
    return __builtin_bit_cast(float, r);
}
template<int M>
__device__ __forceinline__ float lxor(float v, int bp32) {
    if constexpr (M == 1)      { return dppx<0xB1>(v); }
    else if constexpr (M == 2) { return dppx<0x4E>(v); }
    else if constexpr (M == 8) { return dppx<0x128>(v); }
    else if constexpr (M == 4) {
        int r = __builtin_amdgcn_ds_swizzle(__builtin_bit_cast(int, v), 0x101F);
        return __builtin_bit_cast(float, r);
    } else if constexpr (M == 16) {
        int r = __builtin_amdgcn_ds_swizzle(__builtin_bit_cast(int, v), 0x401F);
        return __builtin_bit_cast(float, r);
    } else {
        int r = __builtin_amdgcn_ds_bpermute(bp32, __builtin_bit_cast(int, v));
        return __builtin_bit_cast(float, r);
    }
}
template<int M>
__device__ __forceinline__ f32x2 lxor2(f32x2 z, int bp32) {
    f32x2 p; p.x = lxor<M>(z.x, bp32); p.y = lxor<M>(z.y, bp32); return p;
}

// ---- Rot gates (validated R8) ----
template<bool PK, int LM>
__device__ __forceinline__ void gate_local(St& s, const C2p& u) {
    #pragma unroll
    for (int j0 = 0; j0 < NA; ++j0) {
        if (j0 & LM) continue;
        const int j1 = j0 | LM;
        f32x2 z0 = s.z[j0], z1 = s.z[j1];
        s.z[j0] = Ops<PK>::cmac(z1, u.r01, u.i01, Ops<PK>::cmul(z0, u.r00, u.i00));
        s.z[j1] = Ops<PK>::cmac(z1, u.r11, u.i11, Ops<PK>::cmul(z0, u.r10, u.i10));
    }
}
template<bool PK, int M>
__device__ __forceinline__ void gate_lane(St& s, const C2p& u, int lane, int bp32) {
    const bool b = (lane & M) != 0;
    f32x2 ar = b ? u.r11 : u.r00, ai = b ? u.i11 : u.i00;
    f32x2 br = b ? u.r10 : u.r01, bi = b ? u.i10 : u.i01;
    #pragma unroll
    for (int j = 0; j < NA; ++j) {
        f32x2 p = lxor2<M>(s.z[j], bp32);
        s.z[j] = Ops<PK>::cmac(p, br, bi, Ops<PK>::cmul(s.z[j], ar, ai));
    }
}

// ---- transpose: swap 3 wid bits with 3 j bits (one barrier; validated R7) ----
__device__ __forceinline__ void transpose_wl(St& s, int t, int wid, int lane, f32x2* ex) {
    #pragma unroll
    for (int j = 0; j < NA; ++j) ex[(j<<9) | t] = s.z[j];
    __syncthreads();
    #pragma unroll
    for (int j = 0; j < NA; ++j) s.z[j] = ex[(wid<<9) | (j<<6) | lane];
}

// ---- circuit: direct construction of (ring1 · layer0-Rots · RY) |0>, then layer-1 ----
// L1 layout: y0..y2=j2,j1,j0 | y3..y8=l5..l0 | y9..y11=w2..w0
// x = M1^-1 y (verified against R10's trip_ring1 gray addressing):
//   x0=j2^w0  x1=j1^j2^w0  x2=j0^j1  x3=l5^j0  x4=l4^l5 ... x8=l0^l1
//   x9=w2^l0  x10=w1^w2  x11=w0^w1
template<bool PK>
__device__ __forceinline__ void circuit(St& s, f32x2* ex,
                                        const f32x2 (*rotu)[8],
                                        const float (*fac)[4],
                                        int t, int lane, int wid, int bp32) {
    const int l = lane, W = wid;
    auto ldf = [&](int w, int bit) -> f32x4 {
        return *reinterpret_cast<const f32x4*>(fac[(w << 1) | bit]);  // {re,re,im,im}
    };
    // thread-constant prefix P over wires 4..11
    {
        const int b4  = ((l>>4) ^ (l>>5)) & 1;
        const int b5  = ((l>>3) ^ (l>>4)) & 1;
        const int b6  = ((l>>2) ^ (l>>3)) & 1;
        const int b7  = ((l>>1) ^ (l>>2)) & 1;
        const int b8  = ( l     ^ (l>>1)) & 1;
        const int b9  = ((W>>2) ^  l    ) & 1;
        const int b10 = ((W>>1) ^ (W>>2)) & 1;
        const int b11 = ( W     ^ (W>>1)) & 1;
        f32x4 f = ldf(4, b4);
        f32x2 P = f32x2{f.x, f.z};
        f = ldf(5,  b5);  P = Ops<PK>::cmul(P, f32x2{f.x,f.y}, f32x2{f.z,f.w});
        f = ldf(6,  b6);  P = Ops<PK>::cmul(P, f32x2{f.x,f.y}, f32x2{f.z,f.w});
        f = ldf(7,  b7);  P = Ops<PK>::cmul(P, f32x2{f.x,f.y}, f32x2{f.z,f.w});
        f = ldf(8,  b8);  P = Ops<PK>::cmul(P, f32x2{f.x,f.y}, f32x2{f.z,f.w});
        f = ldf(9,  b9);  P = Ops<PK>::cmul(P, f32x2{f.x,f.y}, f32x2{f.z,f.w});
        f = ldf(10, b10); P = Ops<PK>::cmul(P, f32x2{f.x,f.y}, f32x2{f.z,f.w});
        f = ldf(11, b11); P = Ops<PK>::cmul(P, f32x2{f.x,f.y}, f32x2{f.z,f.w});
        // j-dependent factors; runtime XOR (w0,l5) folded into the table address
        const int w0 = W & 1, l5 = (l >> 5) & 1;
        f32x4 v0a = ldf(0, w0),  v0b = ldf(0, w0 ^ 1);   // index j2
        f32x4 v1a = ldf(1, w0),  v1b = ldf(1, w0 ^ 1);   // index j1^j2
        f32x4 v2a = ldf(2, 0),   v2b = ldf(2, 1);        // index j0^j1
        f32x4 v3a = ldf(3, l5),  v3b = ldf(3, l5 ^ 1);   // index j0
        #pragma unroll
        for (int j = 0; j < NA; ++j) {
            const int a0 = (j >> 2) & 1;
            const int a1 = ((j >> 1) ^ (j >> 2)) & 1;
            const int a2 = (j ^ (j >> 1)) & 1;
            const int a3 = j & 1;
            const f32x4 g0 = a0 ? v0b : v0a;   // compile-time selects
            const f32x4 g1 = a1 ? v1b : v1a;
            const f32x4 g2 = a2 ? v2b : v2a;
            const f32x4 g3 = a3 ? v3b : v3a;
            f32x2 z = Ops<PK>::cmul(P, f32x2{g0.x,g0.y}, f32x2{g0.z,g0.w});
            z = Ops<PK>::cmul(z, f32x2{g1.x,g1.y}, f32x2{g1.z,g1.w});
            z = Ops<PK>::cmul(z, f32x2{g2.x,g2.y}, f32x2{g2.z,g2.w});
            z = Ops<PK>::cmul(z, f32x2{g3.x,g3.y}, f32x2{g3.z,g3.w});
            s.z[j] = z;
        }
    }
    // ===== layer 1 Rot sweep (L1) =====
    auto ld = [&](int g) -> C2p {
        C2p u;
        u.r00 = rotu[g][0]; u.i00 = rotu[g][1];
        u.r01 = rotu[g][2]; u.i01 = rotu[g][3];
        u.r10 = rotu[g][4]; u.i10 = rotu[g][5];
        u.r11 = rotu[g][6]; u.i11 = rotu[g][7];
        return u;
    };
    { C2p u = ld(0);  gate_local<PK,4>(s, u); }            // wire0
    { C2p u = ld(1);  gate_local<PK,2>(s, u); }            // wire1
    { C2p u = ld(2);  gate_local<PK,1>(s, u); }            // wire2
    { C2p u = ld(3);  gate_lane<PK,32>(s, u, lane, bp32); }
    { C2p u = ld(4);  gate_lane<PK,16>(s, u, lane, bp32); }
    { C2p u = ld(5);  gate_lane<PK,8>(s, u, lane, bp32); }
    { C2p u = ld(6);  gate_lane<PK,4>(s, u, lane, bp32); }
    { C2p u = ld(7);  gate_lane<PK,2>(s, u, lane, bp32); }
    { C2p u = ld(8);  gate_lane<PK,1>(s, u, lane, bp32); }
    transpose_wl(s, t, wid, lane, ex);                     // -> L0
    { C2p u = ld(9);  gate_local<PK,4>(s, u); }            // wire9
    { C2p u = ld(10); gate_local<PK,2>(s, u); }
    { C2p u = ld(11); gate_local<PK,1>(s, u); }
    // CNOT ring r=2 fused into epilogue
}

__global__ __launch_bounds__(BT)
void qnn_kernel(const float* __restrict__ x, const float* __restrict__ var,
                const float* __restrict__ hw, const float* __restrict__ hb,
                float* __restrict__ out)
{
    __shared__ f32x2 ex[NA * BT];              // 32 KiB (single buffer)
    __shared__ f32x2 rotu[12][8];              // layer-1 splat matrices
    __shared__ __align__(16) float fac[24][4]; // v_w[b] = {re,re,im,im}
    __shared__ float wavesum[8];

    const int t    = threadIdx.x;
    const int b    = blockIdx.x;
    const int lane = t & 63;
    const int wid  = t >> 6;
    const int bp32 = (lane ^ 32) << 2;

    // packed-op semantics self-check (exact fp32; asm can't fold)
    bool pk_ok;
    {
        f32x2 z = {1.0f, 2.0f}, ur2 = {3.0f, 3.0f}, ui2 = {5.0f, 5.0f}, acc = {0.25f, -0.5f};
        f32x2 r = pkfma_swapneg(z, ui2, pkfma(z, ur2, acc));
        pk_ok = (r.x == -6.75f) && (r.y == 10.5f);
    }

    if (t < 12) {
        // layer-1 Rot matrix for wire t, splatted
        const int g = 12 + t;
        const float phi   = var[g*3+0];
        const float theta = var[g*3+1];
        const float omega = var[g*3+2];
        float st, ct; sincosf(0.5f*theta, &st, &ct);
        float sp, cp; sincosf(-0.5f*(phi+omega), &sp, &cp);
        float sm, cm; sincosf(-0.5f*(phi-omega), &sm, &cm);
        const float v0r =  cp*ct, v0i =  sp*ct;
        const float v1r = -cm*st, v1i =  sm*st;
        const float v2r =  cm*st, v2i =  sm*st;
        const float v3r =  cp*ct, v3i = -sp*ct;
        rotu[t][0] = f32x2{v0r, v0r}; rotu[t][1] = f32x2{v0i, v0i};
        rotu[t][2] = f32x2{v1r, v1r}; rotu[t][3] = f32x2{v1i, v1i};
        rotu[t][4] = f32x2{v2r, v2r}; rotu[t][5] = f32x2{v2i, v2i};
        rotu[t][6] = f32x2{v3r, v3r}; rotu[t][7] = f32x2{v3i, v3i};
    } else if (t < 24) {
        // v_w = Rot^0_w * RY(x_w) |0> for wire w (product-state factor table)
        const int w = t - 12;
        const float phi   = var[w*3+0];
        const float theta = var[w*3+1];
        const float omega = var[w*3+2];
        float st, ct; sincosf(0.5f*theta, &st, &ct);
        float sp, cp; sincosf(-0.5f*(phi+omega), &sp, &cp);
        float sm, cm; sincosf(-0.5f*(phi-omega), &sm, &cm);
        float s_, c_; sincosf(0.5f * x[b*NW + w], &s_, &c_);
        // u00=(cp ct, sp ct) u01=(-cm st, sm st) u10=(cm st, sm st) u11=(cp ct, -sp ct)
        const float v0r = cp*ct*c_ - cm*st*s_;
        const float v0i = sp*ct*c_ + sm*st*s_;
        const float v1r = cm*st*c_ + cp*ct*s_;
        const float v1i = sm*st*c_ - sp*ct*s_;
        fac[w*2+0][0] = v0r; fac[w*2+0][1] = v0r; fac[w*2+0][2] = v0i; fac[w*2+0][3] = v0i;
        fac[w*2+1][0] = v1r; fac[w*2+1][1] = v1r; fac[w*2+1][2] = v1i; fac[w*2+1][3] = v1i;
    }
    __syncthreads();

    St s;
    if (pk_ok) circuit<true >(s, ex, rotu, fac, t, lane, wid, bp32);
    else       circuit<false>(s, ex, rotu, fac, t, lane, wid, bp32);

    // ---- epilogue: probs -> z(M2 x) -> head (ring r=2 fused; validated R10) ----
    // L0: x0=W2 x1=W1 x2=W0 | x3..x8 = l5..l0 | x9=j2 x10=j1 x11=j0
    float h[NW];
    #pragma unroll
    for (int w = 0; w < NW; ++w) h[w] = hw[w];
    const int W = wid, l = lane;
    const int s2 = ((W >> 2) ^ W) & 1;
    const int s3 = ((W >> 1) ^ (l >> 5)) & 1;
    const int s4 = s2 ^ ((l >> 4) & 1);
    const int s5 = s3 ^ ((l >> 3) & 1);
    const int s6 = s4 ^ ((l >> 2) & 1);
    const int s7 = s5 ^ ((l >> 1) & 1);
    const int s8 = s6 ^ (l & 1);
    const int c0 = (W ^ (l >> 4) ^ (l >> 2) ^ l) & 1;
    const int c10 = c0 ^ ((W >> 2) & 1);
    const int c9 = ((W >> 1) ^ (l >> 5) ^ (l >> 3) ^ (l >> 1)) & 1;
    const int c1 = c9 ^ ((W >> 1) & 1);

    const float base =
        (s2 ? -h[2] : h[2]) + (s3 ? -h[3] : h[3]) + (s4 ? -h[4] : h[4]) +
        (s5 ? -h[5] : h[5]) + (s6 ? -h[6] : h[6]) + (s7 ? -h[7] : h[7]) +
        (s8 ? -h[8] : h[8]);
    const float A  = (c0 ? -h[0] : h[0]) + (c10 ? -h[10] : h[10]);   // * (-1)^j1
    const float B  = (c1 ? -h[1] : h[1]) + (c9  ? -h[11] : h[11]);   // * (-1)^(j2^j0)
    const float Cc = (c9 ? -h[9] : h[9]);                            // * (-1)^j2

    float acc = 0.0f;
    #pragma unroll
    for (int j = 0; j < NA; ++j) {
        const float pr = s.z[j].x*s.z[j].x + s.z[j].y*s.z[j].y;
        float zz = base;
        zz += (j & 2) ? -A : A;
        zz += (j & 4) ? -Cc : Cc;
        zz += (((j >> 2) ^ j) & 1) ? -B : B;
        acc += pr * zz;
    }
    #pragma unroll
    for (int off = 32; off > 0; off >>= 1) acc += __shfl_down(acc, off, 64);
    if (lane == 0) wavesum[wid] = acc;
    __syncthreads();
    if (t == 0) {
        float r = hb[0];
        #pragma unroll
        for (int wv = 0; wv < 8; ++wv) r += wavesum[wv];
        out[b] = r;
    }
}

extern "C" void kernel_launch(void* const* d_in, const int* in_sizes, int n_in,
                              void* d_out, int out_size, void* d_ws, size_t ws_size,
                              hipStream_t stream) {
    const float* x   = (const float*)d_in[0];
    const float* var = (const float*)d_in[1];
    const float* hw  = (const float*)d_in[2];
    const float* hb  = (const float*)d_in[3];
    float* out = (float*)d_out;
    qnn_kernel<<<out_size, BT, 0, stream>>>(x, var, hw, hb, out);
}